// Round 6
// baseline (377.806 us; speedup 1.0000x reference)
//
#include <hip/hip_runtime.h>
#include <float.h>

#define MARGIN 0.1f
#define BLK 512          // threads per block (8 waves)
#define ROWS 4           // rows processed per block
#define KCHUNK 4         // float4 chunks per thread per row (BLK*KCHUNK*4 == n)

// Native clang vector types (__builtin_nontemporal_load rejects HIP_vector_type).
typedef float fx4 __attribute__((ext_vector_type(4)));
typedef int   ix4 __attribute__((ext_vector_type(4)));

__device__ __forceinline__ void acc_elem(float s, int tg, int ti, int j, int self_col,
                                         float& pmin, float& nmax) {
    const bool same = (tg == ti);
    const float pv = (same && j != self_col) ? s : FLT_MAX;
    const float nv = same ? -FLT_MAX : s;
    pmin = fminf(pmin, pv);
    nmax = fmaxf(nmax, nv);
}

__device__ __forceinline__ void acc_vec4(fx4 s, ix4 tg, int ti, int j0, int self_col,
                                         float& pmin, float& nmax) {
    acc_elem(s.x, tg.x, ti, j0 + 0, self_col, pmin, nmax);
    acc_elem(s.y, tg.y, ti, j0 + 1, self_col, pmin, nmax);
    acc_elem(s.z, tg.z, ti, j0 + 2, self_col, pmin, nmax);
    acc_elem(s.w, tg.w, ti, j0 + 3, self_col, pmin, nmax);
}

// ---------------- R4 baseline kernel (timing anchor, unchanged) ----------------
__global__ __launch_bounds__(BLK) void triplet_rows_kernel(
    const float* __restrict__ sim,
    const int* __restrict__ targets,
    const int* __restrict__ idx,
    float* __restrict__ row_loss,
    int n)
{
    const int tid = threadIdx.x;
    const int nvec = n >> 2;
    const int i0 = blockIdx.x * ROWS;
    const ix4* __restrict__ tgt4 = (const ix4*)targets;

    ix4 tg[KCHUNK];
    int vbase[KCHUNK];
    #pragma unroll
    for (int k = 0; k < KCHUNK; ++k) {
        const int v = tid + k * BLK;
        vbase[k] = v;
        if (v < nvec) tg[k] = tgt4[v];
    }

    __shared__ float s_p[ROWS][BLK / 64];
    __shared__ float s_n[ROWS][BLK / 64];

    #pragma unroll
    for (int rr = 0; rr < ROWS; ++rr) {
        const int i = i0 + rr;
        if (i >= n) break;
        const int r = idx[i];
        const int ti = targets[i];
        const int self_col = r;
        const fx4* __restrict__ row4 = (const fx4*)(sim + (size_t)r * (size_t)n);

        fx4 s[KCHUNK];
        #pragma unroll
        for (int k = 0; k < KCHUNK; ++k)
            if (vbase[k] < nvec) s[k] = __builtin_nontemporal_load(&row4[vbase[k]]);

        float pmin = FLT_MAX, nmax = -FLT_MAX;
        #pragma unroll
        for (int k = 0; k < KCHUNK; ++k)
            if (vbase[k] < nvec)
                acc_vec4(s[k], tg[k], ti, vbase[k] << 2, self_col, pmin, nmax);

        for (int j = (nvec << 2) + tid; j < n; j += BLK)
            acc_elem(sim[(size_t)r * (size_t)n + j], targets[j], ti, j, self_col,
                     pmin, nmax);

        #pragma unroll
        for (int off = 32; off > 0; off >>= 1) {
            pmin = fminf(pmin, __shfl_down(pmin, off));
            nmax = fmaxf(nmax, __shfl_down(nmax, off));
        }
        const int wave = tid >> 6;
        const int lane = tid & 63;
        if (lane == 0) { s_p[rr][wave] = pmin; s_n[rr][wave] = nmax; }
    }

    __syncthreads();

    if (tid < ROWS) {
        const int i = i0 + tid;
        if (i < n) {
            float p = s_p[tid][0];
            float q = s_n[tid][0];
            #pragma unroll
            for (int w = 1; w < BLK / 64; ++w) {
                p = fminf(p, s_p[tid][w]);
                q = fmaxf(q, s_n[tid][w]);
            }
            row_loss[i] = fmaxf(q - p + MARGIN, 0.0f);
        }
    }
}

// ---------------- Candidate: max-ILP (16 loads in flight, chunk-major) --------
// Preloads ALL 16 float4 sim chunks (4 rows x 4 chunks) back-to-back, then
// accumulates into 4 independent (pmin,nmax) streams; all reductions deferred
// to the end. Removes the per-row load->consume->reduce serialization.
__global__ __launch_bounds__(BLK) void triplet_rows_ilp_kernel(
    const float* __restrict__ sim,
    const int* __restrict__ targets,
    const int* __restrict__ idx,
    float* __restrict__ row_loss,
    int n)
{
    const int tid = threadIdx.x;
    const int nvec = n >> 2;
    const int i0 = blockIdx.x * ROWS;
    const ix4* __restrict__ tgt4 = (const ix4*)targets;

    // targets cached in registers (shared across rows)
    ix4 tg[KCHUNK];
    int vbase[KCHUNK];
    #pragma unroll
    for (int k = 0; k < KCHUNK; ++k) {
        const int v = tid + k * BLK;
        vbase[k] = v;
        if (v < nvec) tg[k] = tgt4[v];
    }

    int rrow[ROWS], ti[ROWS];
    const fx4* row4[ROWS];
    #pragma unroll
    for (int rr = 0; rr < ROWS; ++rr) {
        const int i = (i0 + rr < n) ? (i0 + rr) : (n - 1);   // clamp (dup write ok)
        rrow[rr] = idx[i];
        ti[rr] = targets[i];
        row4[rr] = (const fx4*)(sim + (size_t)rrow[rr] * (size_t)n);
    }

    // Issue all 16 sim loads back-to-back (16 VMEM ops in flight per thread).
    fx4 s[ROWS][KCHUNK];
    #pragma unroll
    for (int rr = 0; rr < ROWS; ++rr)
        #pragma unroll
        for (int k = 0; k < KCHUNK; ++k)
            if (vbase[k] < nvec)
                s[rr][k] = __builtin_nontemporal_load(&row4[rr][vbase[k]]);

    float pmin[ROWS], nmax[ROWS];
    #pragma unroll
    for (int rr = 0; rr < ROWS; ++rr) { pmin[rr] = FLT_MAX; nmax[rr] = -FLT_MAX; }

    #pragma unroll
    for (int rr = 0; rr < ROWS; ++rr)
        #pragma unroll
        for (int k = 0; k < KCHUNK; ++k)
            if (vbase[k] < nvec)
                acc_vec4(s[rr][k], tg[k], ti[rr], vbase[k] << 2, rrow[rr],
                         pmin[rr], nmax[rr]);

    // generic tail for n not matching BLK*KCHUNK*4 — no-op for n=8192
    if (nvec > BLK * KCHUNK || (n & 3)) {
        #pragma unroll
        for (int rr = 0; rr < ROWS; ++rr) {
            for (int v = tid + BLK * KCHUNK; v < nvec; v += BLK) {
                const fx4 sv = __builtin_nontemporal_load(&row4[rr][v]);
                const ix4 tv = tgt4[v];
                acc_vec4(sv, tv, ti[rr], v << 2, rrow[rr], pmin[rr], nmax[rr]);
            }
            for (int j = (nvec << 2) + tid; j < n; j += BLK)
                acc_elem(sim[(size_t)rrow[rr] * (size_t)n + j], targets[j],
                         ti[rr], j, rrow[rr], pmin[rr], nmax[rr]);
        }
    }

    // deferred reductions
    __shared__ float s_p[ROWS][BLK / 64];
    __shared__ float s_n[ROWS][BLK / 64];
    #pragma unroll
    for (int rr = 0; rr < ROWS; ++rr) {
        float p = pmin[rr], q = nmax[rr];
        #pragma unroll
        for (int off = 32; off > 0; off >>= 1) {
            p = fminf(p, __shfl_down(p, off));
            q = fmaxf(q, __shfl_down(q, off));
        }
        const int wave = tid >> 6;
        const int lane = tid & 63;
        if (lane == 0) { s_p[rr][wave] = p; s_n[rr][wave] = q; }
    }
    __syncthreads();

    if (tid < ROWS) {
        const int i = i0 + tid;
        if (i < n) {
            float p = s_p[tid][0];
            float q = s_n[tid][0];
            #pragma unroll
            for (int w = 1; w < BLK / 64; ++w) {
                p = fminf(p, s_p[tid][w]);
                q = fmaxf(q, s_n[tid][w]);
            }
            row_loss[i] = fmaxf(q - p + MARGIN, 0.0f);
        }
    }
}

// ---------------- mean reduce ----------------
__global__ __launch_bounds__(1024) void mean_reduce_kernel(
    const float* __restrict__ row_loss,
    float* __restrict__ out,
    int n)
{
    const int tid = threadIdx.x;
    float acc = 0.0f;
    for (int i = tid; i < n; i += 1024) acc += row_loss[i];

    #pragma unroll
    for (int off = 32; off > 0; off >>= 1)
        acc += __shfl_down(acc, off);

    __shared__ float s_sum[16];
    const int wave = tid >> 6;
    const int lane = tid & 63;
    if (lane == 0) s_sum[wave] = acc;
    __syncthreads();
    if (tid == 0) {
        float total = 0.0f;
        #pragma unroll
        for (int w = 0; w < 16; ++w) total += s_sum[w];
        out[0] = total / (float)n;
    }
}

extern "C" void kernel_launch(void* const* d_in, const int* in_sizes, int n_in,
                              void* d_out, int out_size, void* d_ws, size_t ws_size,
                              hipStream_t stream) {
    const float* sim = (const float*)d_in[0];
    const int* targets = (const int*)d_in[1];
    const int* idx = (const int*)d_in[2];
    const int n = in_sizes[2];

    float* row_loss = (float*)d_ws;
    float* out = (float*)d_out;

    const int grid = (n + ROWS - 1) / ROWS;
    // Anchor (R4 kernel) + candidate: both write identical row_loss values.
    // dur_us minus R4's 336 us == candidate's exact duration.
    triplet_rows_kernel<<<grid, BLK, 0, stream>>>(sim, targets, idx, row_loss, n);
    triplet_rows_ilp_kernel<<<grid, BLK, 0, stream>>>(sim, targets, idx, row_loss, n);
    mean_reduce_kernel<<<1, 1024, 0, stream>>>(row_loss, out, n);
}

// Round 7
// 335.871 us; speedup vs baseline: 1.1249x; 1.1249x over previous
//
#include <hip/hip_runtime.h>
#include <float.h>

#define MARGIN 0.1f
#define BLK 512          // threads per block (8 waves)
#define ROWS 4           // rows processed per block
#define KCHUNK 4         // float4 chunks per thread per row (BLK*KCHUNK*4 == n)

// Native clang vector types (__builtin_nontemporal_load rejects HIP_vector_type).
typedef float fx4 __attribute__((ext_vector_type(4)));
typedef int   ix4 __attribute__((ext_vector_type(4)));

__device__ __forceinline__ void acc_elem(float s, int tg, int ti, int j, int self_col,
                                         float& pmin, float& nmax) {
    const bool same = (tg == ti);
    const float pv = (same && j != self_col) ? s : FLT_MAX;
    const float nv = same ? -FLT_MAX : s;
    pmin = fminf(pmin, pv);
    nmax = fmaxf(nmax, nv);
}

__device__ __forceinline__ void acc_vec4(fx4 s, ix4 tg, int ti, int j0, int self_col,
                                         float& pmin, float& nmax) {
    acc_elem(s.x, tg.x, ti, j0 + 0, self_col, pmin, nmax);
    acc_elem(s.y, tg.y, ti, j0 + 1, self_col, pmin, nmax);
    acc_elem(s.z, tg.z, ti, j0 + 2, self_col, pmin, nmax);
    acc_elem(s.w, tg.w, ti, j0 + 3, self_col, pmin, nmax);
}

// Max-ILP row kernel (measured 42 us in R6's anchor+candidate experiment —
// at the 256 MiB / 6.3 TB/s streaming floor).
// One block = ROWS consecutive output rows. All 16 sim loads (ROWS x KCHUNK
// float4, chunk-major) issue back-to-back before any consumption; targets are
// register-cached once and reused across rows; reductions fully deferred.
__global__ __launch_bounds__(BLK) void triplet_rows_ilp_kernel(
    const float* __restrict__ sim,
    const int* __restrict__ targets,
    const int* __restrict__ idx,
    float* __restrict__ row_loss,
    int n)
{
    const int tid = threadIdx.x;
    const int nvec = n >> 2;
    const int i0 = blockIdx.x * ROWS;
    const ix4* __restrict__ tgt4 = (const ix4*)targets;

    // targets cached in registers (shared across rows)
    ix4 tg[KCHUNK];
    int vbase[KCHUNK];
    #pragma unroll
    for (int k = 0; k < KCHUNK; ++k) {
        const int v = tid + k * BLK;
        vbase[k] = v;
        if (v < nvec) tg[k] = tgt4[v];
    }

    int rrow[ROWS], ti[ROWS];
    const fx4* row4[ROWS];
    #pragma unroll
    for (int rr = 0; rr < ROWS; ++rr) {
        const int i = (i0 + rr < n) ? (i0 + rr) : (n - 1);   // clamp (dup write ok)
        rrow[rr] = idx[i];
        ti[rr] = targets[i];
        row4[rr] = (const fx4*)(sim + (size_t)rrow[rr] * (size_t)n);
    }

    // Issue all 16 sim loads back-to-back (16 VMEM ops in flight per thread).
    fx4 s[ROWS][KCHUNK];
    #pragma unroll
    for (int rr = 0; rr < ROWS; ++rr)
        #pragma unroll
        for (int k = 0; k < KCHUNK; ++k)
            if (vbase[k] < nvec)
                s[rr][k] = __builtin_nontemporal_load(&row4[rr][vbase[k]]);

    float pmin[ROWS], nmax[ROWS];
    #pragma unroll
    for (int rr = 0; rr < ROWS; ++rr) { pmin[rr] = FLT_MAX; nmax[rr] = -FLT_MAX; }

    #pragma unroll
    for (int rr = 0; rr < ROWS; ++rr)
        #pragma unroll
        for (int k = 0; k < KCHUNK; ++k)
            if (vbase[k] < nvec)
                acc_vec4(s[rr][k], tg[k], ti[rr], vbase[k] << 2, rrow[rr],
                         pmin[rr], nmax[rr]);

    // generic tail for n not matching BLK*KCHUNK*4 — no-op for n=8192
    if (nvec > BLK * KCHUNK || (n & 3)) {
        #pragma unroll
        for (int rr = 0; rr < ROWS; ++rr) {
            for (int v = tid + BLK * KCHUNK; v < nvec; v += BLK) {
                const fx4 sv = __builtin_nontemporal_load(&row4[rr][v]);
                const ix4 tv = tgt4[v];
                acc_vec4(sv, tv, ti[rr], v << 2, rrow[rr], pmin[rr], nmax[rr]);
            }
            for (int j = (nvec << 2) + tid; j < n; j += BLK)
                acc_elem(sim[(size_t)rrow[rr] * (size_t)n + j], targets[j],
                         ti[rr], j, rrow[rr], pmin[rr], nmax[rr]);
        }
    }

    // deferred reductions
    __shared__ float s_p[ROWS][BLK / 64];
    __shared__ float s_n[ROWS][BLK / 64];
    #pragma unroll
    for (int rr = 0; rr < ROWS; ++rr) {
        float p = pmin[rr], q = nmax[rr];
        #pragma unroll
        for (int off = 32; off > 0; off >>= 1) {
            p = fminf(p, __shfl_down(p, off));
            q = fmaxf(q, __shfl_down(q, off));
        }
        const int wave = tid >> 6;
        const int lane = tid & 63;
        if (lane == 0) { s_p[rr][wave] = p; s_n[rr][wave] = q; }
    }
    __syncthreads();

    if (tid < ROWS) {
        const int i = i0 + tid;
        if (i < n) {
            float p = s_p[tid][0];
            float q = s_n[tid][0];
            #pragma unroll
            for (int w = 1; w < BLK / 64; ++w) {
                p = fminf(p, s_p[tid][w]);
                q = fmaxf(q, s_n[tid][w]);
            }
            row_loss[i] = fmaxf(q - p + MARGIN, 0.0f);
        }
    }
}

// Mean reduce: single block, deterministic.
__global__ __launch_bounds__(1024) void mean_reduce_kernel(
    const float* __restrict__ row_loss,
    float* __restrict__ out,
    int n)
{
    const int tid = threadIdx.x;
    float acc = 0.0f;
    for (int i = tid; i < n; i += 1024) acc += row_loss[i];

    #pragma unroll
    for (int off = 32; off > 0; off >>= 1)
        acc += __shfl_down(acc, off);

    __shared__ float s_sum[16];
    const int wave = tid >> 6;
    const int lane = tid & 63;
    if (lane == 0) s_sum[wave] = acc;
    __syncthreads();
    if (tid == 0) {
        float total = 0.0f;
        #pragma unroll
        for (int w = 0; w < 16; ++w) total += s_sum[w];
        out[0] = total / (float)n;
    }
}

extern "C" void kernel_launch(void* const* d_in, const int* in_sizes, int n_in,
                              void* d_out, int out_size, void* d_ws, size_t ws_size,
                              hipStream_t stream) {
    const float* sim = (const float*)d_in[0];
    const int* targets = (const int*)d_in[1];
    const int* idx = (const int*)d_in[2];
    const int n = in_sizes[2];

    float* row_loss = (float*)d_ws;
    float* out = (float*)d_out;

    const int grid = (n + ROWS - 1) / ROWS;
    triplet_rows_ilp_kernel<<<grid, BLK, 0, stream>>>(sim, targets, idx, row_loss, n);
    mean_reduce_kernel<<<1, 1024, 0, stream>>>(row_loss, out, n);
}